// Round 7
// baseline (438.506 us; speedup 1.0000x reference)
//
#include <hip/hip_runtime.h>

// ---------------------------------------------------------------------------
// qp = q@Wq.T ; kp = qp@Wk.T (quirk) ; vp = v@Wv.T
// att = softmax(causal(q k^T * sqrt(D))) ; y = att v ; out = y@Wp.T + bp
// Score path split bf16 (hi/lo interleaved, 3-term MFMA) -> ~fp32 logits.
// Round-11 (attn): R6 showed no pipe saturated (VALU 51/LDS ~36/MFMA 21) ->
// latency-bound at 2 waves/SIMD. The pairing (512 uniform blocks) is what
// caps residency at 2 blocks/CU; LDS 48KB allows 3/CU and VGPR=128 allows
// 4 waves/SIMD. So: UNPAIR. Grid 1024 blocks, one q-tile each, DESCENDING
// cost order (qt = 15 - bid/64): 768 long blocks resident at t=0, 256 short
// ones backfill as slots free (backfill replaces pairing as load balance).
// Body/staging/softmax byte-identical to R6. No merge, no state growth.
// ws (6NE u16 = 96 MiB proven): [0,2NE) qsl_i -> kp_i ; [2NE,4NE) qp_i -> wp_b
// [4NE,5NE) vpT ; [5NE,6NE) ybf. d_out scratch (dead before out-proj):
// wq_i 2WE | wk_i 2WE | wv_b WE | vb NE  (27.3 MB < 33.5).
// ---------------------------------------------------------------------------

typedef unsigned short u16;
typedef unsigned int   u32;
typedef __attribute__((ext_vector_type(8))) __bf16 bf16x8;
typedef __attribute__((ext_vector_type(8))) u16    u16x8;
typedef __attribute__((ext_vector_type(4))) u16    u16x4;
typedef __attribute__((ext_vector_type(4))) float  f32x4;
typedef __attribute__((ext_vector_type(4))) int    i32x4;

#define DEV static __device__ __forceinline__

DEV u16 f2bf(float x){ union{float f;u32 u;}v; v.f=x; u32 r=v.u+0x7fffu+((v.u>>16)&1u); return (u16)(r>>16); }
DEV float bf2f(u16 b){ union{u32 u;float f;}v; v.u=((u32)b)<<16; return v.f; }
DEV f32x4 zero4(){ f32x4 z={0.f,0.f,0.f,0.f}; return z; }
DEV f32x4 mfma16(bf16x8 a, bf16x8 b, f32x4 c){ return __builtin_amdgcn_mfma_f32_16x16x32_bf16(a,b,c,0,0,0); }
DEV void gld16(const u16* g, u16* l){
  __builtin_amdgcn_global_load_lds((const __attribute__((address_space(1))) u32*)g,
                                   (__attribute__((address_space(3))) u32*)l, 16, 0, 0);
}
DEV u32 cvtpk(float lo, float hi){
  u32 r;
  asm("v_cvt_pk_bf16_f32 %0, %1, %2" : "=v"(r) : "v"(lo), "v"(hi));
  return r;
}
DEV float max3(float a, float b, float c){
  float d;
  asm("v_max3_f32 %0, %1, %2, %3" : "=v"(d) : "v"(a), "v"(b), "v"(c));
  return d;
}

constexpr int B_=4, T_=2048, E_=1024;
constexpr int M_=B_*T_;                  // 8192
constexpr float L2E8 = 11.5415603f;      // 8/ln2 (quirk scale folded into exp2)

// ---------------------------------------------------------------------------
__global__ __launch_bounds__(256)
void cvt_a(const float* __restrict__ q, const float* __restrict__ v,
           u16* __restrict__ qi, u16* __restrict__ vb)
{
  const int j=blockIdx.y;
  const size_t e=((size_t)blockIdx.x*256+threadIdx.x)*8;
  const float* s=(j==0)?q:v;
  f32x4 x0=*reinterpret_cast<const f32x4*>(s+e);
  f32x4 x1=*reinterpret_cast<const f32x4*>(s+e+4);
  u16x8 h,l;
#pragma unroll
  for(int t=0;t<4;t++){
    u16 hh=f2bf(x0[t]); h[t]=hh; l[t]=f2bf(x0[t]-bf2f(hh));
    u16 h2=f2bf(x1[t]); h[t+4]=h2; l[t+4]=f2bf(x1[t]-bf2f(h2));
  }
  if(j==0){
    const size_t row=e>>10, k=e&1023;
    u16* d=qi + row*2048 + (k>>3)*16;
    *reinterpret_cast<u16x8*>(d)=h;
    *reinterpret_cast<u16x8*>(d+8)=l;
  } else {
    *reinterpret_cast<u16x8*>(vb+e)=h;
  }
}

__global__ __launch_bounds__(256)
void cvt_w(const float* __restrict__ Wq, const float* __restrict__ Wk, const float* __restrict__ Wv,
           u16* __restrict__ wqi, u16* __restrict__ wki, u16* __restrict__ wvb)
{
  const int j=blockIdx.y;
  const size_t e=((size_t)blockIdx.x*256+threadIdx.x)*8;
  const float* s=(j==0)?Wq:(j==1)?Wk:Wv;
  f32x4 x0=*reinterpret_cast<const f32x4*>(s+e);
  f32x4 x1=*reinterpret_cast<const f32x4*>(s+e+4);
  u16x8 h,l;
#pragma unroll
  for(int t=0;t<4;t++){
    u16 hh=f2bf(x0[t]); h[t]=hh; l[t]=f2bf(x0[t]-bf2f(hh));
    u16 h2=f2bf(x1[t]); h[t+4]=h2; l[t+4]=f2bf(x1[t]-bf2f(h2));
  }
  if(j==2){ *reinterpret_cast<u16x8*>(wvb+e)=h; return; }
  u16* base=(j==0)?wqi:wki;
  const size_t row=e>>10, k=e&1023;
  u16* d=base + row*2048 + (k>>3)*16;
  *reinterpret_cast<u16x8*>(d)=h;
  *reinterpret_cast<u16x8*>(d+8)=l;
}

__global__ __launch_bounds__(256)
void cvt_p(const float* __restrict__ Wp, u16* __restrict__ wpb)
{
  const size_t e=((size_t)blockIdx.x*256+threadIdx.x)*8;
  f32x4 x0=*reinterpret_cast<const f32x4*>(Wp+e);
  f32x4 x1=*reinterpret_cast<const f32x4*>(Wp+e+4);
  u16x8 h;
#pragma unroll
  for(int t=0;t<4;t++){ h[t]=f2bf(x0[t]); h[t+4]=f2bf(x1[t]); }
  *reinterpret_cast<u16x8*>(wpb+e)=h;
}

// ---------------------------------------------------------------------------
// GEMM C[M',N'] = A[M',K] @ B[N',K]^T, K=1024, BK=64. 128x128 tile, 4 waves
// (2x2 of 64x64). All staging via global_load_lds with XOR chunk swizzle
// phys = logical ^ (row&7).
// SPLIT: interleaved hi/lo operands (row = 2048 u16), 96 MFMA/iter.
// OMODE: 0 split-interleaved out ; 1 plain bf16 out (ldc) ; 2 fp32+bias (ldc).
// ---------------------------------------------------------------------------
template<int SPLIT,int OMODE>
__global__ __launch_bounds__(256)
void gemm(const u16* __restrict__ Ag, const u16* __restrict__ Bg,
          const float* __restrict__ bias,
          u16* __restrict__ Ob, float* __restrict__ Of, int ldc)
{
  __shared__ u16 sA[SPLIT?128*128:128*64];
  __shared__ u16 sB[SPLIT?128*128:128*64];

  const int tid=threadIdx.x, wave=tid>>6, lane=tid&63;
  const int quad=lane>>4, l16=lane&15, sw=l16&7;
  const int wm=(wave>>1)*64, wn=(wave&1)*64;
  const int n0=blockIdx.x*128, m0=blockIdx.y*128;

  f32x4 acc[4][4];
#pragma unroll
  for(int i=0;i<4;i++)
#pragma unroll
    for(int j=0;j<4;j++) acc[i][j]=zero4();

  for(int k0=0;k0<E_;k0+=64){
    if(SPLIT){
      // 2048 chunks each (128 rows x 16), swizzled
#pragma unroll
      for(int it=0;it<8;it++){
        const int c=it*256+tid, row=c>>4, j=(c&15)^(row&7);
        gld16(Ag + (size_t)(m0+row)*2048 + k0*2 + j*8, &sA[(it*256+wave*64)*8]);
      }
#pragma unroll
      for(int it=0;it<8;it++){
        const int c=it*256+tid, row=c>>4, j=(c&15)^(row&7);
        gld16(Bg + (size_t)(n0+row)*2048 + k0*2 + j*8, &sB[(it*256+wave*64)*8]);
      }
    } else {
      // 1024 chunks each (128 rows x 8), swizzled
#pragma unroll
      for(int it=0;it<4;it++){
        const int c=it*256+tid, row=c>>3, j=(c&7)^(row&7);
        gld16(Ag + (size_t)(m0+row)*1024 + k0 + j*8, &sA[(it*256+wave*64)*8]);
      }
#pragma unroll
      for(int it=0;it<4;it++){
        const int c=it*256+tid, row=c>>3, j=(c&7)^(row&7);
        gld16(Bg + (size_t)(n0+row)*1024 + k0 + j*8, &sB[(it*256+wave*64)*8]);
      }
    }
    __syncthreads();

#pragma unroll
    for(int kk=0;kk<2;kk++){
      if(SPLIT){
        bf16x8 ahh[4],ahl[4],bhh[4],bhl[4];
#pragma unroll
        for(int i=0;i<4;i++){
          const u16* pa=&sA[(wm+i*16+l16)*128];
          const u16* pb=&sB[(wn+i*16+l16)*128];
          const int ch=2*(kk*4+quad);
          ahh[i]=*reinterpret_cast<const bf16x8*>(&pa[((ch  )^sw)*8]);
          ahl[i]=*reinterpret_cast<const bf16x8*>(&pa[((ch+1)^sw)*8]);
          bhh[i]=*reinterpret_cast<const bf16x8*>(&pb[((ch  )^sw)*8]);
          bhl[i]=*reinterpret_cast<const bf16x8*>(&pb[((ch+1)^sw)*8]);
        }
#pragma unroll
        for(int i=0;i<4;i++)
#pragma unroll
          for(int j=0;j<4;j++){
            acc[i][j]=mfma16(ahh[i],bhh[j],acc[i][j]);
            acc[i][j]=mfma16(ahh[i],bhl[j],acc[i][j]);
            acc[i][j]=mfma16(ahl[i],bhh[j],acc[i][j]);
          }
      } else {
        bf16x8 a[4],b[4];
#pragma unroll
        for(int i=0;i<4;i++){
          a[i]=*reinterpret_cast<const bf16x8*>(&sA[(wm+i*16+l16)*64 + (((kk*4+quad)^sw)*8)]);
          b[i]=*reinterpret_cast<const bf16x8*>(&sB[(wn+i*16+l16)*64 + (((kk*4+quad)^sw)*8)]);
        }
#pragma unroll
        for(int i=0;i<4;i++)
#pragma unroll
          for(int j=0;j<4;j++)
            acc[i][j]=mfma16(a[i],b[j],acc[i][j]);
      }
    }
    __syncthreads();
  }

  // epilogue: D row=quad*4+r, col=l16 (verified)
#pragma unroll
  for(int i=0;i<4;i++)
#pragma unroll
    for(int j=0;j<4;j++){
      const int col=n0+wn+j*16+l16;
#pragma unroll
      for(int r=0;r<4;r++){
        const int row=m0+wm+i*16+quad*4+r;
        float v=acc[i][j][r];
        if(OMODE==2)      Of[(size_t)row*ldc+col]=v+bias[col];
        else if(OMODE==1) Ob[(size_t)row*ldc+col]=f2bf(v);
        else {
          u16 hh=f2bf(v);
          const size_t base=(size_t)row*2048 + (size_t)(col>>3)*16 + (col&7);
          Ob[base]=hh; Ob[base+8]=f2bf(v-bf2f(hh));
        }
      }
    }
}

// ---------------------------------------------------------------------------
// Flash attention, S^T orientation (R6 body). K (interleaved hi/lo) AND V^T
// staged via global_load_lds with XOR swizzle; double-buffered LDS (48KB),
// 1 barrier/tile. UNPAIRED: grid 1024 blocks, one 128-row q-tile each,
// descending cost (qt = 15 - bid/64) -> 3 blocks/CU resident, short blocks
// backfill. VALU diet kept: zero-C first MFMA, v_max3 trees, l via
// ones-MFMA, cvt_pk pack, defer-max, setprio on MFMA clusters.
// ---------------------------------------------------------------------------
__global__ __launch_bounds__(256)
void attn(const u16* __restrict__ qpi, const u16* __restrict__ kpi,
          const u16* __restrict__ vpT, u16* __restrict__ yout)
{
  __shared__ u16 sK [2][64*128];        // 32 KB
  __shared__ u16 sVT[2][64*64];         // 16 KB, [d][s] swizzled

  const int tid=threadIdx.x, wave=tid>>6, lane=tid&63;
  const int quad=lane>>4, l16=lane&15, sw=l16&7;
  const int qt=15-((int)blockIdx.x>>6); // descending cost: long blocks first
  const int bh=blockIdx.x&63;
  const int b=bh>>4, h=bh&15;
  const int qr0=qt*128+wave*32;

  const f32x4 FZ=zero4();               // hoisted MFMA C-zero
  bf16x8 ONES;                          // all-ones A-frag for l row-sum
  {
    u16x8 o={0x3f80,0x3f80,0x3f80,0x3f80,0x3f80,0x3f80,0x3f80,0x3f80};
    ONES=*reinterpret_cast<bf16x8*>(&o);
  }

  auto STAGE=[&](int buf, int kt2){
    const int s0=kt2*64;
    // K tile: 1024 chunks (64 rows x 16), swizzled
#pragma unroll
    for(int it=0;it<4;it++){
      const int c=it*256+tid, row=c>>4, j=(c&15)^(row&7);
      gld16(kpi + (size_t)(b*T_+s0+row)*2048 + h*128 + j*8,
            &sK[buf][(it*256+wave*64)*8]);
    }
    // V^T tile: 512 chunks (64 d-rows x 8), swizzled, from vpT
#pragma unroll
    for(int it=0;it<2;it++){
      const int c=it*256+tid, row=c>>3, j=(c&7)^(row&7);
      gld16(vpT + (size_t)(h*64+row)*8192 + b*T_ + s0 + j*8,
            &sVT[buf][(it*256+wave*64)*8]);
    }
  };

  bf16x8 qfh[2][2], qfl[2][2];
#pragma unroll
  for(int mt=0;mt<2;mt++)
#pragma unroll
    for(int ksv=0;ksv<2;ksv++){
      const size_t off=(size_t)(b*T_+qr0+mt*16+l16)*2048 + h*128 + (ksv*4+quad)*16;
      qfh[mt][ksv]=*reinterpret_cast<const bf16x8*>(qpi+off);
      qfl[mt][ksv]=*reinterpret_cast<const bf16x8*>(qpi+off+8);
    }

  float mst[2]={-1e30f,-1e30f};
  f32x4 lacc[2]={FZ,FZ};                // l row-sums via ones-MFMA
  f32x4 oacc[2][4];
#pragma unroll
  for(int mt=0;mt<2;mt++)
#pragma unroll
    for(int dt=0;dt<4;dt++) oacc[mt][dt]=zero4();

  const int nkt=2*(qt+1);
  STAGE(0, 0);
  __syncthreads();                      // implicit vmcnt drain: buf0 ready

  for(int kt=0;kt<nkt;kt++){
    const int cur=kt&1;
    if(kt+1<nkt) STAGE(cur^1, kt+1);    // issue next-tile loads early
    const int s0=kt*64;

    if(s0<=qr0+31){
      // ---- S^T = K Q^T, 3-term split (first MFMA takes C=FZ) ----
      f32x4 sacc[4][2];
      __builtin_amdgcn_s_setprio(1);
#pragma unroll
      for(int st=0;st<4;st++)
#pragma unroll
        for(int ksv=0;ksv<2;ksv++){
          const u16* pk=&sK[cur][(st*16+l16)*128];
          const int ch=2*(ksv*4+quad);
          bf16x8 kh=*reinterpret_cast<const bf16x8*>(&pk[((ch  )^sw)*8]);
          bf16x8 kl=*reinterpret_cast<const bf16x8*>(&pk[((ch+1)^sw)*8]);
#pragma unroll
          for(int mt=0;mt<2;mt++){
            sacc[st][mt]=mfma16(kh,qfh[mt][ksv], (ksv==0)?FZ:sacc[st][mt]);
            sacc[st][mt]=mfma16(kl,qfh[mt][ksv],sacc[st][mt]);
            sacc[st][mt]=mfma16(kh,qfl[mt][ksv],sacc[st][mt]);
          }
        }
      __builtin_amdgcn_s_setprio(0);
      const bool needmask=(s0+63>qr0);
      u32 pk_[4][2][2];
      // ---- online softmax (x8 folded into exp2; l via ones-MFMA) ----
#pragma unroll
      for(int mt=0;mt<2;mt++){
        const int qrow=qr0+mt*16+l16;
        float v_[16];
#pragma unroll
        for(int st=0;st<4;st++)
#pragma unroll
          for(int r=0;r<4;r++){
            float v=sacc[st][mt][r];
            if(needmask && (s0+st*16+quad*4+r>qrow)) v=-1e30f;
            sacc[st][mt][r]=v;
            v_[st*4+r]=v;
          }
        float m0=max3(v_[0],v_[1],v_[2]);
        float m1=max3(v_[3],v_[4],v_[5]);
        float m2=max3(v_[6],v_[7],v_[8]);
        float m3=max3(v_[9],v_[10],v_[11]);
        float m4=max3(v_[12],v_[13],v_[14]);
        float mloc=fmaxf(max3(m0,m1,m2), max3(m3,m4,v_[15]));
        mloc=fmaxf(mloc,__shfl_xor(mloc,16,64));
        mloc=fmaxf(mloc,__shfl_xor(mloc,32,64));
        float cexp;
        if(__all(mloc <= mst[mt]+1.0f)){
          cexp=mst[mt]*L2E8;            // defer: keep old max, P<=e^8
        } else {
          const float nm=fmaxf(mst[mt],mloc);
          const float alpha=exp2f((mst[mt]-nm)*L2E8);
          mst[mt]=nm;
          lacc[mt]*=alpha;
#pragma unroll
          for(int dt=0;dt<4;dt++) oacc[mt][dt]*=alpha;
          cexp=nm*L2E8;
        }
#pragma unroll
        for(int st=0;st<4;st++){
#pragma unroll
          for(int r=0;r<4;r++){
            float p=exp2f(__builtin_fmaf(sacc[st][mt][r],L2E8,-cexp));
            sacc[st][mt][r]=p;
          }
          pk_[st][mt][0]=cvtpk(sacc[st][mt][0],sacc[st][mt][1]);
          pk_[st][mt][1]=cvtpk(sacc[st][mt][2],sacc[st][mt][3]);
        }
      }
      // ---- P^T C-layout -> PV B-frag via shfl; O^T += V^T P ; l += 1^T P
      const int srcA=(2*(quad&1))*16+l16, srcB=srcA+16;
      const bool hs=(quad>=2);
#pragma unroll
      for(int ksv=0;ksv<2;ksv++){
        bf16x8 b2[2];
#pragma unroll
        for(int mt=0;mt<2;mt++){
          int e0=__shfl((int)pk_[2*ksv  ][mt][0],srcA,64);
          int g0=__shfl((int)pk_[2*ksv+1][mt][0],srcA,64);
          int e1=__shfl((int)pk_[2*ksv  ][mt][1],srcA,64);
          int g1=__shfl((int)pk_[2*ksv+1][mt][1],srcA,64);
          int e2=__shfl((int)pk_[2*ksv  ][mt][0],srcB,64);
          int g2=__shfl((int)pk_[2*ksv+1][mt][0],srcB,64);
          int e3=__shfl((int)pk_[2*ksv  ][mt][1],srcB,64);
          int g3=__shfl((int)pk_[2*ksv+1][mt][1],srcB,64);
          i32x4 bd={ hs?g0:e0, hs?g1:e1, hs?g2:e2, hs?g3:e3 };
          b2[mt]=*reinterpret_cast<bf16x8*>(&bd);
        }
        __builtin_amdgcn_s_setprio(1);
        lacc[0]=mfma16(ONES,b2[0],lacc[0]);
        lacc[1]=mfma16(ONES,b2[1],lacc[1]);
#pragma unroll
        for(int dt=0;dt<4;dt++){
          bf16x8 va=*reinterpret_cast<const bf16x8*>(&sVT[cur][(dt*16+l16)*64 + (((ksv*4+quad)^sw)*8)]);
#pragma unroll
          for(int mt=0;mt<2;mt++)
            oacc[mt][dt]=mfma16(va,b2[mt],oacc[mt][dt]);
        }
        __builtin_amdgcn_s_setprio(0);
      }
    }
    __syncthreads();                    // drains next-tile vmcnt + protects cur
  }

  // ---- y = O/l (lacc already holds the full 64-s sums per lane) ----
#pragma unroll
  for(int mt=0;mt<2;mt++){
    const float inv=1.0f/lacc[mt][0];
    const size_t rb=(size_t)(b*T_+qr0+mt*16+l16)*1024 + h*64;
#pragma unroll
    for(int dt=0;dt<4;dt++){
      u16x4 o4;
#pragma unroll
      for(int r=0;r<4;r++) o4[r]=f2bf(oacc[mt][dt][r]*inv);
      *reinterpret_cast<u16x4*>(yout + rb + dt*16 + quad*4)=o4;
    }
  }
}

// ---------------------------------------------------------------------------
extern "C" void kernel_launch(void* const* d_in, const int* in_sizes, int n_in,
                              void* d_out, int out_size, void* d_ws, size_t ws_size,
                              hipStream_t stream)
{
  const float* q =(const float*)d_in[0];
  // d_in[1] (k) UNUSED: reference quirk computes kp from qp.
  const float* v =(const float*)d_in[2];
  const float* Wq=(const float*)d_in[3];
  const float* Wk=(const float*)d_in[4];
  const float* Wv=(const float*)d_in[5];
  const float* Wp=(const float*)d_in[6];
  const float* bp=(const float*)d_in[7];
  float* out=(float*)d_out;

  const size_t NE=(size_t)M_*E_;          // 8.39M
  const size_t WE=(size_t)E_*E_;          // 1.05M
  u16* wsv=(u16*)d_ws;
  u16* qsl_i=wsv;                         // [0,2NE): qsplit_i, later kp_i
  u16* qp_i =wsv+2*NE;                    // [2NE,4NE): qp_i, later wp_b
  u16* kp_i =wsv;                         // alias (qsplit dead after G1)
  u16* wp_b =wsv+2*NE;                    // alias (qp dead after attn)
  u16* vpT  =wsv+4*NE;                    // [4NE,5NE)
  u16* ybf  =wsv+5*NE;                    // [5NE,6NE)
  u16* og   =(u16*)d_out;                 // scratch, dead before out-proj
  u16* wq_i =og;                          // 2WE
  u16* wk_i =og+2*WE;                     // 2WE
  u16* wv_b =og+4*WE;                     // WE
  u16* vb   =og+5*WE;                     // NE

  dim3 blk(256);
  cvt_a<<<dim3(NE/2048,2), blk, 0, stream>>>(q, v, qsl_i, vb);
  cvt_w<<<dim3(WE/2048,3), blk, 0, stream>>>(Wq, Wk, Wv, wq_i, wk_i, wv_b);

  dim3 g(E_/128, M_/128);                 // (8, 64)
  // qp = qsplit @ Wq^T  (split)
  gemm<1,0><<<g, blk, 0, stream>>>(qsl_i, wq_i, nullptr, qp_i, nullptr, 0);
  // kp = qp @ Wk^T  (split)
  gemm<1,0><<<g, blk, 0, stream>>>(qp_i, wk_i, nullptr, kp_i, nullptr, 0);
  // vpT[e][b*T+t] = Wv @ v^T  (plain, operand-swapped, ldc=8192)
  gemm<0,1><<<dim3(M_/128, E_/128), blk, 0, stream>>>(wv_b, vb, nullptr, vpT, nullptr, M_);
  // attention -> ybf (unpaired, descending-cost: 1024 blocks, 3/CU resident)
  attn<<<dim3(1024), blk, 0, stream>>>(qp_i, kp_i, vpT, ybf);
  // Wp -> bf16 into dead qp region
  cvt_p<<<dim3(WE/2048), blk, 0, stream>>>(Wp, wp_b);
  // out = ybf @ Wp^T + bp
  gemm<0,2><<<g, blk, 0, stream>>>(ybf, wp_b, bp, nullptr, out, E_);
}

// Round 9
// 419.300 us; speedup vs baseline: 1.0458x; 1.0458x over previous
//
#include <hip/hip_runtime.h>

// ---------------------------------------------------------------------------
// qp = q@Wq.T ; kp = qp@Wk.T (quirk) ; vp = v@Wv.T
// att = softmax(causal(q k^T * sqrt(D))) ; y = att v ; out = y@Wp.T + bp
// Score path split bf16 (hi/lo interleaved, 3-term MFMA) -> ~fp32 logits.
// Round-13 == Round-12 resubmit (R8 bench was an infra failure: container
// acquisition, not a kernel error). attn frozen (6 variants all ~143us;
// structural floor). Target the constant 291us non-attn side: GEMM grid
// (8,64) puts column x on XCD=id%8=x -> every XCD streams ALL of A through
// its private L2 (256MB/split-GEMM vs 32 ideal). SWAP grid mapping for
// G1/G2/G4 to (64,8) row-fastest: XCD=row%8, all column-blocks of a row-
// panel share one XCD, A fetched once per XCD-set (A 256->32MB, B 4->32MB,
// net -196MB/split-GEMM, -114MB out-proj). G3 already row-major-lucky.
// attn byte-identical to R7 (control).
// ws (6NE u16 = 96 MiB proven): [0,2NE) qsl_i -> kp_i ; [2NE,4NE) qp_i -> wp_b
// [4NE,5NE) vpT ; [5NE,6NE) ybf. d_out scratch (dead before out-proj):
// wq_i 2WE | wk_i 2WE | wv_b WE | vb NE  (27.3 MB < 33.5).
// ---------------------------------------------------------------------------

typedef unsigned short u16;
typedef unsigned int   u32;
typedef __attribute__((ext_vector_type(8))) __bf16 bf16x8;
typedef __attribute__((ext_vector_type(8))) u16    u16x8;
typedef __attribute__((ext_vector_type(4))) u16    u16x4;
typedef __attribute__((ext_vector_type(4))) float  f32x4;
typedef __attribute__((ext_vector_type(4))) int    i32x4;

#define DEV static __device__ __forceinline__

DEV u16 f2bf(float x){ union{float f;u32 u;}v; v.f=x; u32 r=v.u+0x7fffu+((v.u>>16)&1u); return (u16)(r>>16); }
DEV float bf2f(u16 b){ union{u32 u;float f;}v; v.u=((u32)b)<<16; return v.f; }
DEV f32x4 zero4(){ f32x4 z={0.f,0.f,0.f,0.f}; return z; }
DEV f32x4 mfma16(bf16x8 a, bf16x8 b, f32x4 c){ return __builtin_amdgcn_mfma_f32_16x16x32_bf16(a,b,c,0,0,0); }
DEV void gld16(const u16* g, u16* l){
  __builtin_amdgcn_global_load_lds((const __attribute__((address_space(1))) u32*)g,
                                   (__attribute__((address_space(3))) u32*)l, 16, 0, 0);
}
DEV u32 cvtpk(float lo, float hi){
  u32 r;
  asm("v_cvt_pk_bf16_f32 %0, %1, %2" : "=v"(r) : "v"(lo), "v"(hi));
  return r;
}
DEV float max3(float a, float b, float c){
  float d;
  asm("v_max3_f32 %0, %1, %2, %3" : "=v"(d) : "v"(a), "v"(b), "v"(c));
  return d;
}

constexpr int B_=4, T_=2048, E_=1024;
constexpr int M_=B_*T_;                  // 8192
constexpr float L2E8 = 11.5415603f;      // 8/ln2 (quirk scale folded into exp2)

// ---------------------------------------------------------------------------
__global__ __launch_bounds__(256)
void cvt_a(const float* __restrict__ q, const float* __restrict__ v,
           u16* __restrict__ qi, u16* __restrict__ vb)
{
  const int j=blockIdx.y;
  const size_t e=((size_t)blockIdx.x*256+threadIdx.x)*8;
  const float* s=(j==0)?q:v;
  f32x4 x0=*reinterpret_cast<const f32x4*>(s+e);
  f32x4 x1=*reinterpret_cast<const f32x4*>(s+e+4);
  u16x8 h,l;
#pragma unroll
  for(int t=0;t<4;t++){
    u16 hh=f2bf(x0[t]); h[t]=hh; l[t]=f2bf(x0[t]-bf2f(hh));
    u16 h2=f2bf(x1[t]); h[t+4]=h2; l[t+4]=f2bf(x1[t]-bf2f(h2));
  }
  if(j==0){
    const size_t row=e>>10, k=e&1023;
    u16* d=qi + row*2048 + (k>>3)*16;
    *reinterpret_cast<u16x8*>(d)=h;
    *reinterpret_cast<u16x8*>(d+8)=l;
  } else {
    *reinterpret_cast<u16x8*>(vb+e)=h;
  }
}

__global__ __launch_bounds__(256)
void cvt_w(const float* __restrict__ Wq, const float* __restrict__ Wk, const float* __restrict__ Wv,
           u16* __restrict__ wqi, u16* __restrict__ wki, u16* __restrict__ wvb)
{
  const int j=blockIdx.y;
  const size_t e=((size_t)blockIdx.x*256+threadIdx.x)*8;
  const float* s=(j==0)?Wq:(j==1)?Wk:Wv;
  f32x4 x0=*reinterpret_cast<const f32x4*>(s+e);
  f32x4 x1=*reinterpret_cast<const f32x4*>(s+e+4);
  u16x8 h,l;
#pragma unroll
  for(int t=0;t<4;t++){
    u16 hh=f2bf(x0[t]); h[t]=hh; l[t]=f2bf(x0[t]-bf2f(hh));
    u16 h2=f2bf(x1[t]); h[t+4]=h2; l[t+4]=f2bf(x1[t]-bf2f(h2));
  }
  if(j==2){ *reinterpret_cast<u16x8*>(wvb+e)=h; return; }
  u16* base=(j==0)?wqi:wki;
  const size_t row=e>>10, k=e&1023;
  u16* d=base + row*2048 + (k>>3)*16;
  *reinterpret_cast<u16x8*>(d)=h;
  *reinterpret_cast<u16x8*>(d+8)=l;
}

__global__ __launch_bounds__(256)
void cvt_p(const float* __restrict__ Wp, u16* __restrict__ wpb)
{
  const size_t e=((size_t)blockIdx.x*256+threadIdx.x)*8;
  f32x4 x0=*reinterpret_cast<const f32x4*>(Wp+e);
  f32x4 x1=*reinterpret_cast<const f32x4*>(Wp+e+4);
  u16x8 h;
#pragma unroll
  for(int t=0;t<4;t++){ h[t]=f2bf(x0[t]); h[t+4]=f2bf(x1[t]); }
  *reinterpret_cast<u16x8*>(wpb+e)=h;
}

// ---------------------------------------------------------------------------
// GEMM C[M',N'] = A[M',K] @ B[N',K]^T, K=1024, BK=64. 128x128 tile, 4 waves
// (2x2 of 64x64). All staging via global_load_lds with XOR chunk swizzle
// phys = logical ^ (row&7).
// SPLIT: interleaved hi/lo operands (row = 2048 u16), 96 MFMA/iter.
// OMODE: 0 split-interleaved out ; 1 plain bf16 out (ldc) ; 2 fp32+bias (ldc).
// SWAP: 1 -> m0 from blockIdx.x (row-fastest grid): XCD=row%8, column-blocks
// of one A row-panel share an XCD -> A fetched once per XCD-set, not 8x.
// ---------------------------------------------------------------------------
template<int SPLIT,int OMODE,int SWAP>
__global__ __launch_bounds__(256)
void gemm(const u16* __restrict__ Ag, const u16* __restrict__ Bg,
          const float* __restrict__ bias,
          u16* __restrict__ Ob, float* __restrict__ Of, int ldc)
{
  __shared__ u16 sA[SPLIT?128*128:128*64];
  __shared__ u16 sB[SPLIT?128*128:128*64];

  const int tid=threadIdx.x, wave=tid>>6, lane=tid&63;
  const int quad=lane>>4, l16=lane&15, sw=l16&7;
  const int wm=(wave>>1)*64, wn=(wave&1)*64;
  const int n0=(SWAP?blockIdx.y:blockIdx.x)*128;
  const int m0=(SWAP?blockIdx.x:blockIdx.y)*128;

  f32x4 acc[4][4];
#pragma unroll
  for(int i=0;i<4;i++)
#pragma unroll
    for(int j=0;j<4;j++) acc[i][j]=zero4();

  for(int k0=0;k0<E_;k0+=64){
    if(SPLIT){
      // 2048 chunks each (128 rows x 16), swizzled
#pragma unroll
      for(int it=0;it<8;it++){
        const int c=it*256+tid, row=c>>4, j=(c&15)^(row&7);
        gld16(Ag + (size_t)(m0+row)*2048 + k0*2 + j*8, &sA[(it*256+wave*64)*8]);
      }
#pragma unroll
      for(int it=0;it<8;it++){
        const int c=it*256+tid, row=c>>4, j=(c&15)^(row&7);
        gld16(Bg + (size_t)(n0+row)*2048 + k0*2 + j*8, &sB[(it*256+wave*64)*8]);
      }
    } else {
      // 1024 chunks each (128 rows x 8), swizzled
#pragma unroll
      for(int it=0;it<4;it++){
        const int c=it*256+tid, row=c>>3, j=(c&7)^(row&7);
        gld16(Ag + (size_t)(m0+row)*1024 + k0 + j*8, &sA[(it*256+wave*64)*8]);
      }
#pragma unroll
      for(int it=0;it<4;it++){
        const int c=it*256+tid, row=c>>3, j=(c&7)^(row&7);
        gld16(Bg + (size_t)(n0+row)*1024 + k0 + j*8, &sB[(it*256+wave*64)*8]);
      }
    }
    __syncthreads();

#pragma unroll
    for(int kk=0;kk<2;kk++){
      if(SPLIT){
        bf16x8 ahh[4],ahl[4],bhh[4],bhl[4];
#pragma unroll
        for(int i=0;i<4;i++){
          const u16* pa=&sA[(wm+i*16+l16)*128];
          const u16* pb=&sB[(wn+i*16+l16)*128];
          const int ch=2*(kk*4+quad);
          ahh[i]=*reinterpret_cast<const bf16x8*>(&pa[((ch  )^sw)*8]);
          ahl[i]=*reinterpret_cast<const bf16x8*>(&pa[((ch+1)^sw)*8]);
          bhh[i]=*reinterpret_cast<const bf16x8*>(&pb[((ch  )^sw)*8]);
          bhl[i]=*reinterpret_cast<const bf16x8*>(&pb[((ch+1)^sw)*8]);
        }
#pragma unroll
        for(int i=0;i<4;i++)
#pragma unroll
          for(int j=0;j<4;j++){
            acc[i][j]=mfma16(ahh[i],bhh[j],acc[i][j]);
            acc[i][j]=mfma16(ahh[i],bhl[j],acc[i][j]);
            acc[i][j]=mfma16(ahl[i],bhh[j],acc[i][j]);
          }
      } else {
        bf16x8 a[4],b[4];
#pragma unroll
        for(int i=0;i<4;i++){
          a[i]=*reinterpret_cast<const bf16x8*>(&sA[(wm+i*16+l16)*64 + (((kk*4+quad)^sw)*8)]);
          b[i]=*reinterpret_cast<const bf16x8*>(&sB[(wn+i*16+l16)*64 + (((kk*4+quad)^sw)*8)]);
        }
#pragma unroll
        for(int i=0;i<4;i++)
#pragma unroll
          for(int j=0;j<4;j++)
            acc[i][j]=mfma16(a[i],b[j],acc[i][j]);
      }
    }
    __syncthreads();
  }

  // epilogue: D row=quad*4+r, col=l16 (verified)
#pragma unroll
  for(int i=0;i<4;i++)
#pragma unroll
    for(int j=0;j<4;j++){
      const int col=n0+wn+j*16+l16;
#pragma unroll
      for(int r=0;r<4;r++){
        const int row=m0+wm+i*16+quad*4+r;
        float v=acc[i][j][r];
        if(OMODE==2)      Of[(size_t)row*ldc+col]=v+bias[col];
        else if(OMODE==1) Ob[(size_t)row*ldc+col]=f2bf(v);
        else {
          u16 hh=f2bf(v);
          const size_t base=(size_t)row*2048 + (size_t)(col>>3)*16 + (col&7);
          Ob[base]=hh; Ob[base+8]=f2bf(v-bf2f(hh));
        }
      }
    }
}

// ---------------------------------------------------------------------------
// Flash attention, S^T orientation (R7, unchanged — control). K (interleaved
// hi/lo) AND V^T staged via global_load_lds with XOR swizzle; dbuf LDS
// (48KB), 1 barrier/tile. Grid 1024 blocks, one 128-row q-tile each,
// descending cost (qt = 15 - bid/64). Same-(b,h) blocks share an XCD
// (bh%8) -> K/V L2-local (FETCH ~55MB corroborates).
// ---------------------------------------------------------------------------
__global__ __launch_bounds__(256)
void attn(const u16* __restrict__ qpi, const u16* __restrict__ kpi,
          const u16* __restrict__ vpT, u16* __restrict__ yout)
{
  __shared__ u16 sK [2][64*128];        // 32 KB
  __shared__ u16 sVT[2][64*64];         // 16 KB, [d][s] swizzled

  const int tid=threadIdx.x, wave=tid>>6, lane=tid&63;
  const int quad=lane>>4, l16=lane&15, sw=l16&7;
  const int qt=15-((int)blockIdx.x>>6); // descending cost: long blocks first
  const int bh=blockIdx.x&63;
  const int b=bh>>4, h=bh&15;
  const int qr0=qt*128+wave*32;

  const f32x4 FZ=zero4();               // hoisted MFMA C-zero
  bf16x8 ONES;                          // all-ones A-frag for l row-sum
  {
    u16x8 o={0x3f80,0x3f80,0x3f80,0x3f80,0x3f80,0x3f80,0x3f80,0x3f80};
    ONES=*reinterpret_cast<bf16x8*>(&o);
  }

  auto STAGE=[&](int buf, int kt2){
    const int s0=kt2*64;
    // K tile: 1024 chunks (64 rows x 16), swizzled
#pragma unroll
    for(int it=0;it<4;it++){
      const int c=it*256+tid, row=c>>4, j=(c&15)^(row&7);
      gld16(kpi + (size_t)(b*T_+s0+row)*2048 + h*128 + j*8,
            &sK[buf][(it*256+wave*64)*8]);
    }
    // V^T tile: 512 chunks (64 d-rows x 8), swizzled, from vpT
#pragma unroll
    for(int it=0;it<2;it++){
      const int c=it*256+tid, row=c>>3, j=(c&7)^(row&7);
      gld16(vpT + (size_t)(h*64+row)*8192 + b*T_ + s0 + j*8,
            &sVT[buf][(it*256+wave*64)*8]);
    }
  };

  bf16x8 qfh[2][2], qfl[2][2];
#pragma unroll
  for(int mt=0;mt<2;mt++)
#pragma unroll
    for(int ksv=0;ksv<2;ksv++){
      const size_t off=(size_t)(b*T_+qr0+mt*16+l16)*2048 + h*128 + (ksv*4+quad)*16;
      qfh[mt][ksv]=*reinterpret_cast<const bf16x8*>(qpi+off);
      qfl[mt][ksv]=*reinterpret_cast<const bf16x8*>(qpi+off+8);
    }

  float mst[2]={-1e30f,-1e30f};
  f32x4 lacc[2]={FZ,FZ};                // l row-sums via ones-MFMA
  f32x4 oacc[2][4];
#pragma unroll
  for(int mt=0;mt<2;mt++)
#pragma unroll
    for(int dt=0;dt<4;dt++) oacc[mt][dt]=zero4();

  const int nkt=2*(qt+1);
  STAGE(0, 0);
  __syncthreads();                      // implicit vmcnt drain: buf0 ready

  for(int kt=0;kt<nkt;kt++){
    const int cur=kt&1;
    if(kt+1<nkt) STAGE(cur^1, kt+1);    // issue next-tile loads early
    const int s0=kt*64;

    if(s0<=qr0+31){
      // ---- S^T = K Q^T, 3-term split (first MFMA takes C=FZ) ----
      f32x4 sacc[4][2];
      __builtin_amdgcn_s_setprio(1);
#pragma unroll
      for(int st=0;st<4;st++)
#pragma unroll
        for(int ksv=0;ksv<2;ksv++){
          const u16* pk=&sK[cur][(st*16+l16)*128];
          const int ch=2*(ksv*4+quad);
          bf16x8 kh=*reinterpret_cast<const bf16x8*>(&pk[((ch  )^sw)*8]);
          bf16x8 kl=*reinterpret_cast<const bf16x8*>(&pk[((ch+1)^sw)*8]);
#pragma unroll
          for(int mt=0;mt<2;mt++){
            sacc[st][mt]=mfma16(kh,qfh[mt][ksv], (ksv==0)?FZ:sacc[st][mt]);
            sacc[st][mt]=mfma16(kl,qfh[mt][ksv],sacc[st][mt]);
            sacc[st][mt]=mfma16(kh,qfl[mt][ksv],sacc[st][mt]);
          }
        }
      __builtin_amdgcn_s_setprio(0);
      const bool needmask=(s0+63>qr0);
      u32 pk_[4][2][2];
      // ---- online softmax (x8 folded into exp2; l via ones-MFMA) ----
#pragma unroll
      for(int mt=0;mt<2;mt++){
        const int qrow=qr0+mt*16+l16;
        float v_[16];
#pragma unroll
        for(int st=0;st<4;st++)
#pragma unroll
          for(int r=0;r<4;r++){
            float v=sacc[st][mt][r];
            if(needmask && (s0+st*16+quad*4+r>qrow)) v=-1e30f;
            sacc[st][mt][r]=v;
            v_[st*4+r]=v;
          }
        float m0=max3(v_[0],v_[1],v_[2]);
        float m1=max3(v_[3],v_[4],v_[5]);
        float m2=max3(v_[6],v_[7],v_[8]);
        float m3=max3(v_[9],v_[10],v_[11]);
        float m4=max3(v_[12],v_[13],v_[14]);
        float mloc=fmaxf(max3(m0,m1,m2), max3(m3,m4,v_[15]));
        mloc=fmaxf(mloc,__shfl_xor(mloc,16,64));
        mloc=fmaxf(mloc,__shfl_xor(mloc,32,64));
        float cexp;
        if(__all(mloc <= mst[mt]+1.0f)){
          cexp=mst[mt]*L2E8;            // defer: keep old max, P<=e^8
        } else {
          const float nm=fmaxf(mst[mt],mloc);
          const float alpha=exp2f((mst[mt]-nm)*L2E8);
          mst[mt]=nm;
          lacc[mt]*=alpha;
#pragma unroll
          for(int dt=0;dt<4;dt++) oacc[mt][dt]*=alpha;
          cexp=nm*L2E8;
        }
#pragma unroll
        for(int st=0;st<4;st++){
#pragma unroll
          for(int r=0;r<4;r++){
            float p=exp2f(__builtin_fmaf(sacc[st][mt][r],L2E8,-cexp));
            sacc[st][mt][r]=p;
          }
          pk_[st][mt][0]=cvtpk(sacc[st][mt][0],sacc[st][mt][1]);
          pk_[st][mt][1]=cvtpk(sacc[st][mt][2],sacc[st][mt][3]);
        }
      }
      // ---- P^T C-layout -> PV B-frag via shfl; O^T += V^T P ; l += 1^T P
      const int srcA=(2*(quad&1))*16+l16, srcB=srcA+16;
      const bool hs=(quad>=2);
#pragma unroll
      for(int ksv=0;ksv<2;ksv++){
        bf16x8 b2[2];
#pragma unroll
        for(int mt=0;mt<2;mt++){
          int e0=__shfl((int)pk_[2*ksv  ][mt][0],srcA,64);
          int g0=__shfl((int)pk_[2*ksv+1][mt][0],srcA,64);
          int e1=__shfl((int)pk_[2*ksv  ][mt][1],srcA,64);
          int g1=__shfl((int)pk_[2*ksv+1][mt][1],srcA,64);
          int e2=__shfl((int)pk_[2*ksv  ][mt][0],srcB,64);
          int g2=__shfl((int)pk_[2*ksv+1][mt][0],srcB,64);
          int e3=__shfl((int)pk_[2*ksv  ][mt][1],srcB,64);
          int g3=__shfl((int)pk_[2*ksv+1][mt][1],srcB,64);
          i32x4 bd={ hs?g0:e0, hs?g1:e1, hs?g2:e2, hs?g3:e3 };
          b2[mt]=*reinterpret_cast<bf16x8*>(&bd);
        }
        __builtin_amdgcn_s_setprio(1);
        lacc[0]=mfma16(ONES,b2[0],lacc[0]);
        lacc[1]=mfma16(ONES,b2[1],lacc[1]);
#pragma unroll
        for(int dt=0;dt<4;dt++){
          bf16x8 va=*reinterpret_cast<const bf16x8*>(&sVT[cur][(dt*16+l16)*64 + (((ksv*4+quad)^sw)*8)]);
#pragma unroll
          for(int mt=0;mt<2;mt++)
            oacc[mt][dt]=mfma16(va,b2[mt],oacc[mt][dt]);
        }
        __builtin_amdgcn_s_setprio(0);
      }
    }
    __syncthreads();                    // drains next-tile vmcnt + protects cur
  }

  // ---- y = O/l (lacc already holds the full 64-s sums per lane) ----
#pragma unroll
  for(int mt=0;mt<2;mt++){
    const float inv=1.0f/lacc[mt][0];
    const size_t rb=(size_t)(b*T_+qr0+mt*16+l16)*1024 + h*64;
#pragma unroll
    for(int dt=0;dt<4;dt++){
      u16x4 o4;
#pragma unroll
      for(int r=0;r<4;r++) o4[r]=f2bf(oacc[mt][dt][r]*inv);
      *reinterpret_cast<u16x4*>(yout + rb + dt*16 + quad*4)=o4;
    }
  }
}

// ---------------------------------------------------------------------------
extern "C" void kernel_launch(void* const* d_in, const int* in_sizes, int n_in,
                              void* d_out, int out_size, void* d_ws, size_t ws_size,
                              hipStream_t stream)
{
  const float* q =(const float*)d_in[0];
  // d_in[1] (k) UNUSED: reference quirk computes kp from qp.
  const float* v =(const float*)d_in[2];
  const float* Wq=(const float*)d_in[3];
  const float* Wk=(const float*)d_in[4];
  const float* Wv=(const float*)d_in[5];
  const float* Wp=(const float*)d_in[6];
  const float* bp=(const float*)d_in[7];
  float* out=(float*)d_out;

  const size_t NE=(size_t)M_*E_;          // 8.39M
  const size_t WE=(size_t)E_*E_;          // 1.05M
  u16* wsv=(u16*)d_ws;
  u16* qsl_i=wsv;                         // [0,2NE): qsplit_i, later kp_i
  u16* qp_i =wsv+2*NE;                    // [2NE,4NE): qp_i, later wp_b
  u16* kp_i =wsv;                         // alias (qsplit dead after G1)
  u16* wp_b =wsv+2*NE;                    // alias (qp dead after attn)
  u16* vpT  =wsv+4*NE;                    // [4NE,5NE)
  u16* ybf  =wsv+5*NE;                    // [5NE,6NE)
  u16* og   =(u16*)d_out;                 // scratch, dead before out-proj
  u16* wq_i =og;                          // 2WE
  u16* wk_i =og+2*WE;                     // 2WE
  u16* wv_b =og+4*WE;                     // WE
  u16* vb   =og+5*WE;                     // NE

  dim3 blk(256);
  cvt_a<<<dim3(NE/2048,2), blk, 0, stream>>>(q, v, qsl_i, vb);
  cvt_w<<<dim3(WE/2048,3), blk, 0, stream>>>(Wq, Wk, Wv, wq_i, wk_i, wv_b);

  dim3 gs(M_/128, E_/128);                // (64, 8) row-fastest (XCD=row%8)
  // qp = qsplit @ Wq^T  (split, swapped grid)
  gemm<1,0,1><<<gs, blk, 0, stream>>>(qsl_i, wq_i, nullptr, qp_i, nullptr, 0);
  // kp = qp @ Wk^T  (split, swapped grid)
  gemm<1,0,1><<<gs, blk, 0, stream>>>(qp_i, wk_i, nullptr, kp_i, nullptr, 0);
  // vpT[e][b*T+t] = Wv @ v^T  (plain, operand-swapped, ldc=8192; grid already
  // XCD-favorable: big operand vb shared within an XCD)
  gemm<0,1,0><<<dim3(M_/128, E_/128), blk, 0, stream>>>(wv_b, vb, nullptr, vpT, nullptr, M_);
  // attention -> ybf (unchanged control: 1024 blocks, descending cost)
  attn<<<dim3(1024), blk, 0, stream>>>(qp_i, kp_i, vpT, ybf);
  // Wp -> bf16 into dead qp region
  cvt_p<<<dim3(WE/2048), blk, 0, stream>>>(Wp, wp_b);
  // out = ybf @ Wp^T + bp  (swapped grid)
  gemm<0,2,1><<<gs, blk, 0, stream>>>(ybf, wp_b, bp, nullptr, out, E_);
}